// Round 1
// baseline (339.337 us; speedup 1.0000x reference)
//
#include <hip/hip_runtime.h>
#include <hip/hip_bf16.h>

// Problem: b=2, t=4096, emb=512, heads=8, head_dim=64.
// out = softmax((xWq^T)(xWk^T)^T / sqrt(512)) (xWv^T) Wu^T + bu
// All GEMMs in bf16 MFMA (threshold = 2% of ref absmax -> plenty of headroom).

#define T 4096
#define HEADS 8
#define HD 64
#define EMB 512
#define BATCH 2
#define BH (BATCH * HEADS)

typedef __attribute__((ext_vector_type(8))) short short8;
typedef __attribute__((ext_vector_type(4))) float floatx4;

// f32 -> bf16 with round-to-nearest-even
__device__ inline short f2bf(float f) {
  union { float f; unsigned u; } v; v.f = f;
  unsigned r = v.u + 0x7FFF + ((v.u >> 16) & 1);
  return (short)(r >> 16);
}

__device__ inline short8 pack8(float4 a, float4 b) {
  short8 o;
  o[0] = f2bf(a.x); o[1] = f2bf(a.y); o[2] = f2bf(a.z); o[3] = f2bf(a.w);
  o[4] = f2bf(b.x); o[5] = f2bf(b.y); o[6] = f2bf(b.z); o[7] = f2bf(b.w);
  return o;
}

// swizzled byte offset inside a [rows][64] bf16 tile (row stride 128B).
// XOR of (row&7)<<4 keeps 16B alignment, kills the 128B-stride bank conflict.
__device__ inline int swz(int row, int byte) {
  return (row * 128 + byte) ^ ((row & 7) << 4);
}

// ---------------------------------------------------------------------------
// Kernel A: q/k/v projections as one [65536 x 64] @ [64 x 64]^T GEMM per matrix.
// Row r of the "A" matrix = 64-elem chunk r of x; r = (b*T + t)*8 + h.
// Outputs bf16 in [bh][t][d] layout.
// ---------------------------------------------------------------------------
__global__ __launch_bounds__(256) void qkv_kernel(
    const float* __restrict__ x, const float* __restrict__ Wq,
    const float* __restrict__ Wk, const float* __restrict__ Wv,
    short* __restrict__ q_ws, short* __restrict__ k_ws, short* __restrict__ v_ws) {
  __shared__ __align__(16) short xs[256 * 64];
  const int tid = threadIdx.x;
  const int lane = tid & 63;
  const int w = tid >> 6;
  const int g = lane >> 4, lr = lane & 15;
  const long rowbase = (long)blockIdx.x * 256;

  // stage 256 rows of x as bf16 (swizzled). Each thread handles one row.
  {
    const float4* xv = (const float4*)(x + (rowbase + tid) * 64);
    for (int c = 0; c < 8; ++c) {
      float4 a = xv[2 * c], b = xv[2 * c + 1];
      *(short8*)((char*)xs + swz(tid, c * 16)) = pack8(a, b);
    }
  }
  __syncthreads();

  const float* Ws[3] = {Wq, Wk, Wv};
  short* outs[3] = {q_ws, k_ws, v_ws};
  for (int m = 0; m < 3; ++m) {
    const float* W = Ws[m];
    short* op = outs[m];
    for (int nt = 0; nt < 4; ++nt) {
      const int coln = nt * 16 + lr;
      // B-fragment: B[k][col] = W[col][k], element j of half kh = W[col][kh*32+8g+j]
      const float4* wr0 = (const float4*)(W + coln * 64 + 8 * g);
      const float4* wr1 = (const float4*)(W + coln * 64 + 32 + 8 * g);
      short8 b0 = pack8(wr0[0], wr0[1]);
      short8 b1 = pack8(wr1[0], wr1[1]);
      for (int mr = 0; mr < 4; ++mr) {
        const int arow = w * 64 + mr * 16 + lr;
        short8 a0 = *(short8*)((char*)xs + swz(arow, g * 16));
        short8 a1 = *(short8*)((char*)xs + swz(arow, 64 + g * 16));
        floatx4 acc = 0;
        acc = __builtin_amdgcn_mfma_f32_16x16x32_bf16(a0, b0, acc, 0, 0, 0);
        acc = __builtin_amdgcn_mfma_f32_16x16x32_bf16(a1, b1, acc, 0, 0, 0);
        // C layout: row = 4g + jj (within 16-row subtile), col = lr
        for (int jj = 0; jj < 4; ++jj) {
          long R = rowbase + w * 64 + mr * 16 + 4 * g + jj;
          int bb = (int)(R >> 15);
          int h = (int)(R & 7);
          int t = (int)((R >> 3) & 4095);
          op[(((long)(bb * HEADS + h) * T + t) * 64) + coln] = f2bf(acc[jj]);
        }
      }
    }
  }
}

// ---------------------------------------------------------------------------
// Kernel B: flash attention, non-causal, scale 1/sqrt(512).
// Block = 64 q-rows (4 waves x 16), KV tiles of 64 keys staged in LDS.
// ---------------------------------------------------------------------------
__global__ __launch_bounds__(256) void attn_kernel(
    const short* __restrict__ q_ws, const short* __restrict__ k_ws,
    const short* __restrict__ v_ws, short* __restrict__ o_ws) {
  __shared__ __align__(16) short Ks[64 * 64];        // [key][d], swizzled
  __shared__ __align__(16) short Vs[64 * 64];        // [d][key] (transposed), swizzled
  __shared__ __align__(16) short Ps[4][16 * 64];     // per-wave P tile [row][key]
  const int tid = threadIdx.x;
  const int lane = tid & 63;
  const int w = tid >> 6;
  const int g = lane >> 4, lr = lane & 15;
  const int bh = blockIdx.y;
  const int q0 = blockIdx.x * 64;
  const long base = (long)bh * T * 64;
  const short* Qp = q_ws + base;
  const short* Kp = k_ws + base;
  const short* Vp = v_ws + base;
  short* Pw = (short*)Ps[w];

  const float c2 = 0.0441941738241592f * 1.4426950408889634f;  // scale * log2(e)

  // Q fragments for this wave's 16 rows (held in registers for the whole loop)
  const int qrow = q0 + w * 16 + lr;
  short8 aq0 = *(const short8*)(Qp + (long)qrow * 64 + g * 8);
  short8 aq1 = *(const short8*)(Qp + (long)qrow * 64 + 32 + g * 8);

  floatx4 acc[4];
  for (int dt = 0; dt < 4; ++dt) acc[dt] = 0;
  float m2[4] = {-1e30f, -1e30f, -1e30f, -1e30f};
  float ell[4] = {0.f, 0.f, 0.f, 0.f};

  for (int kv = 0; kv < T; kv += 64) {
    // ---- stage K tile [key][d] (coalesced 32B/thread) ----
    {
      int key = tid >> 2, dp = (tid & 3) * 16;
      const short8* src = (const short8*)(Kp + (long)(kv + key) * 64 + dp);
      short8 v0 = src[0], v1 = src[1];
      *(short8*)((char*)Ks + swz(key, dp * 2)) = v0;
      *(short8*)((char*)Ks + swz(key, dp * 2 + 16)) = v1;
    }
    // ---- stage V tile transposed -> Vs[d][key] ----
    {
      int key = lane, dp = w * 16;
      const short8* src = (const short8*)(Vp + (long)(kv + key) * 64 + dp);
      short8 v0 = src[0], v1 = src[1];
      for (int jj = 0; jj < 8; ++jj) {
        *(short*)((char*)Vs + swz(dp + jj, key * 2)) = v0[jj];
        *(short*)((char*)Vs + swz(dp + 8 + jj, key * 2)) = v1[jj];
      }
    }
    __syncthreads();

    // ---- QK^T: S[16 q][64 key] as 4 col-tiles ----
    floatx4 s[4];
    for (int kt = 0; kt < 4; ++kt) {
      int key = kt * 16 + lr;
      short8 b0 = *(short8*)((char*)Ks + swz(key, g * 16));
      short8 b1 = *(short8*)((char*)Ks + swz(key, 64 + g * 16));
      floatx4 z = 0;
      z = __builtin_amdgcn_mfma_f32_16x16x32_bf16(aq0, b0, z, 0, 0, 0);
      z = __builtin_amdgcn_mfma_f32_16x16x32_bf16(aq1, b1, z, 0, 0, 0);
      s[kt] = z;
    }

    // ---- online softmax (C-layout: lane holds rows 4g+j, col lr+16kt) ----
    float cf[4];
    for (int j = 0; j < 4; ++j) {
      float tm = fmaxf(fmaxf(s[0][j], s[1][j]), fmaxf(s[2][j], s[3][j]));
      for (int off = 8; off >= 1; off >>= 1)
        tm = fmaxf(tm, __shfl_xor(tm, off, 16));
      float mn = fmaxf(m2[j], tm * c2);
      cf[j] = exp2f(m2[j] - mn);
      m2[j] = mn;
    }
    float ts[4] = {0.f, 0.f, 0.f, 0.f};
    for (int kt = 0; kt < 4; ++kt) {
      for (int j = 0; j < 4; ++j) {
        float p = exp2f(s[kt][j] * c2 - m2[j]);
        ts[j] += p;
        *(short*)((char*)Pw + swz(4 * g + j, (kt * 16 + lr) * 2)) = f2bf(p);
      }
    }
    for (int j = 0; j < 4; ++j) {
      float t = ts[j];
      for (int off = 8; off >= 1; off >>= 1)
        t += __shfl_xor(t, off, 16);
      ell[j] = ell[j] * cf[j] + t;
      for (int dt = 0; dt < 4; ++dt) acc[dt][j] *= cf[j];
    }

    // ---- PV: acc[16 q][64 d] += P[16][64] * V[64][64] ----
    short8 ap0 = *(short8*)((char*)Pw + swz(lr, g * 16));
    short8 ap1 = *(short8*)((char*)Pw + swz(lr, 64 + g * 16));
    for (int dt = 0; dt < 4; ++dt) {
      int d = dt * 16 + lr;
      short8 b0 = *(short8*)((char*)Vs + swz(d, g * 16));
      short8 b1 = *(short8*)((char*)Vs + swz(d, 64 + g * 16));
      acc[dt] = __builtin_amdgcn_mfma_f32_16x16x32_bf16(ap0, b0, acc[dt], 0, 0, 0);
      acc[dt] = __builtin_amdgcn_mfma_f32_16x16x32_bf16(ap1, b1, acc[dt], 0, 0, 0);
    }
    __syncthreads();
  }

  // epilogue: O[b][t][h*64+d] bf16
  const int bb = bh >> 3, h = bh & 7;
  for (int j = 0; j < 4; ++j) {
    float rl = 1.0f / ell[j];
    int trow = q0 + w * 16 + 4 * g + j;
    long obase = ((long)(bb * T + trow)) * EMB + h * 64;
    for (int dt = 0; dt < 4; ++dt)
      o_ws[obase + dt * 16 + lr] = f2bf(acc[dt][j] * rl);
  }
}

// ---------------------------------------------------------------------------
// Kernel C: out[8192][512] = O[8192][512] @ Wu^T + bu  (f32 out)
// Block tile 64x64, K chunks of 64.
// ---------------------------------------------------------------------------
__global__ __launch_bounds__(256) void proj_kernel(
    const short* __restrict__ o_ws, const float* __restrict__ Wu,
    const float* __restrict__ bu, float* __restrict__ out) {
  __shared__ __align__(16) short As[64 * 64];
  __shared__ __align__(16) short Bs[64 * 64];
  const int tid = threadIdx.x;
  const int lane = tid & 63, w = tid >> 6;
  const int g = lane >> 4, lr = lane & 15;
  const int m0 = blockIdx.x * 64;
  const int n0 = blockIdx.y * 64;

  floatx4 acc[4];
  for (int nt = 0; nt < 4; ++nt) acc[nt] = 0;

  for (int kc = 0; kc < EMB; kc += 64) {
    {
      int row = tid >> 2, kp = (tid & 3) * 16;
      const short8* src = (const short8*)(o_ws + (long)(m0 + row) * EMB + kc + kp);
      short8 v0 = src[0], v1 = src[1];
      *(short8*)((char*)As + swz(row, kp * 2)) = v0;
      *(short8*)((char*)As + swz(row, kp * 2 + 16)) = v1;
    }
    {
      int n = tid >> 2, kp = (tid & 3) * 16;
      const float4* src = (const float4*)(Wu + (long)(n0 + n) * EMB + kc + kp);
      *(short8*)((char*)Bs + swz(n, kp * 2)) = pack8(src[0], src[1]);
      *(short8*)((char*)Bs + swz(n, kp * 2 + 16)) = pack8(src[2], src[3]);
    }
    __syncthreads();

    int arow = w * 16 + lr;
    short8 a0 = *(short8*)((char*)As + swz(arow, g * 16));
    short8 a1 = *(short8*)((char*)As + swz(arow, 64 + g * 16));
    for (int nt = 0; nt < 4; ++nt) {
      int n = nt * 16 + lr;
      short8 b0 = *(short8*)((char*)Bs + swz(n, g * 16));
      short8 b1 = *(short8*)((char*)Bs + swz(n, 64 + g * 16));
      acc[nt] = __builtin_amdgcn_mfma_f32_16x16x32_bf16(a0, b0, acc[nt], 0, 0, 0);
      acc[nt] = __builtin_amdgcn_mfma_f32_16x16x32_bf16(a1, b1, acc[nt], 0, 0, 0);
    }
    __syncthreads();
  }

  for (int nt = 0; nt < 4; ++nt) {
    float bias = bu[n0 + nt * 16 + lr];
    for (int j = 0; j < 4; ++j) {
      int mrow = m0 + w * 16 + 4 * g + j;
      out[(long)mrow * EMB + n0 + nt * 16 + lr] = acc[nt][j] + bias;
    }
  }
}

extern "C" void kernel_launch(void* const* d_in, const int* in_sizes, int n_in,
                              void* d_out, int out_size, void* d_ws, size_t ws_size,
                              hipStream_t stream) {
  const float* x  = (const float*)d_in[0];
  const float* Wq = (const float*)d_in[1];
  const float* Wk = (const float*)d_in[2];
  const float* Wv = (const float*)d_in[3];
  const float* Wu = (const float*)d_in[4];
  const float* bu = (const float*)d_in[5];
  float* out = (float*)d_out;

  const long per = (long)BH * T * 64;  // elements per q/k/v buffer
  short* q_ws = (short*)d_ws;
  short* k_ws = q_ws + per;
  short* v_ws = k_ws + per;
  short* o_ws = v_ws + per;  // [8192][512] bf16

  // A: 65536 rows / 256 rows per block
  qkv_kernel<<<256, 256, 0, stream>>>(x, Wq, Wk, Wv, q_ws, k_ws, v_ws);
  // B: 64 q-blocks x 16 (b,h)
  attn_kernel<<<dim3(T / 64, BH), 256, 0, stream>>>(q_ws, k_ws, v_ws, o_ws);
  // C: 8192/64 x 512/64
  proj_kernel<<<dim3(BATCH * T / 64, EMB / 64), 256, 0, stream>>>(o_ws, Wu, bu, out);
}